// Round 7
// baseline (699.408 us; speedup 1.0000x reference)
//
#include <hip/hip_runtime.h>

// MorphologicalLayer: ops='co', windows=[51,25] on [16, 8, 262144] f32.
//   y1 = max51(zp(x)); y2 = min51(zp(y1)); y3 = min25(zp(y2)); y4 = max25(zp(y3))
// Interior tiles fuse min51∘min25 = min75 (3 stages); the two edge tiles run
// the exact 4-stage chain with per-stage zero clamps.
// Two-level (blocked-8 + cascade) suffix/prefix scans in registers; own
// 32-elem block lives in registers across stages (loaded straight from
// global); halo re-read from LDS; final stage stores directly to global
// (masked 8B NT stores) — no final writeback, no copy-out pass.

#define L_ROW   262144
#define N_ROWS  128          // B*C = 16*8
#define BLOCK   256
#define E       32           // elements per thread
#define EF4     8            // E/4
#define T_VALID 7996         // valid outputs per tile (4-aligned)
#define N_TILES 33           // ceil(262144 / 7996)
#define BUF_SLOTS 2048       // 32 KiB exactly -> 5 blocks/CU LDS-wise

typedef float f32x2 __attribute__((ext_vector_type(2)));

// XOR swizzle at float4 granularity: spreads per-thread 128B-strided accesses
// across all 8 bank-quads. Involution, bijective on mult-of-8 ranges.
__device__ __forceinline__ int swz(int s) { return s ^ ((s >> 3) & 7); }

template<bool MX>
__device__ __forceinline__ float mm(float a, float b) {
  return MX ? fmaxf(a, b) : fminf(a, b);
}

__device__ __forceinline__ void edge_zero(float* r, int goff, int tid, bool edge) {
  if (edge) {
    const int base = goff + tid * E;
#pragma unroll
    for (int i = 0; i < E; ++i)
      if ((unsigned)(base + i) >= (unsigned)L_ROW) r[i] = 0.0f;
  }
}

__device__ __forceinline__ void writeback(const float* r, float4* buf, int b4) {
#pragma unroll
  for (int j = 0; j < EF4; ++j)
    buf[swz(b4 + j)] = make_float4(r[4*j], r[4*j+1], r[4*j+2], r[4*j+3]);
  __syncthreads();
}

// K in {51, 75}: all windows [i, i+K-1], i in [0,32), straddle the boundary
// at 32. out[i] = mm(S[i], Base&Top prefix at i+K-1). Always writes back.
template<int K, bool MX>
__device__ __forceinline__ void stage_big(float* r, float4* buf, int tid,
                                          int goff, bool edge) {
  constexpr int BLEN = K - 33;              // 18 / 42 (== 2 mod 4)
  constexpr int BN   = (BLEN + 2) / 4;      // 5 / 11 base-side f4 slots
  const int b4 = tid * EF4;
  const int bh = min(b4, 2032 - BN);        // max slot bh+15+BN <= 2047

  // Base = mm over halo floats [32 .. K-2], lane-wise accumulators
  float4 v0 = buf[swz(bh + 8)];
  float a0 = v0.x, a1 = v0.y, a2 = v0.z, a3 = v0.w;
#pragma unroll
  for (int j = 1; j < BN - 1; ++j) {
    float4 v = buf[swz(bh + 8 + j)];
    a0 = mm<MX>(a0, v.x); a1 = mm<MX>(a1, v.y);
    a2 = mm<MX>(a2, v.z); a3 = mm<MX>(a3, v.w);
  }
  float4 vl = buf[swz(bh + 8 + BN - 1)];    // 2 base floats + T[0], T[1]
  const float Base = mm<MX>(mm<MX>(mm<MX>(a0, a1), mm<MX>(a2, a3)),
                            mm<MX>(vl.x, vl.y));
  // Top: halo floats [K-1 .. K+30]
  float T[34];
  T[0] = vl.z; T[1] = vl.w;
#pragma unroll
  for (int j = 0; j < 8; ++j) {
    float4 v = buf[swz(bh + 8 + BN + j)];
    T[2+4*j] = v.x; T[3+4*j] = v.y; T[4+4*j] = v.z; T[5+4*j] = v.w;
  }
  __syncthreads();   // all halo reads complete before any in-place write

  // S[i] = mm(r[i..31]) via blocked-8 suffix + cascade (in place)
#pragma unroll
  for (int b = 0; b < 4; ++b)
#pragma unroll
    for (int i = 8*b + 6; i >= 8*b; --i) r[i] = mm<MX>(r[i], r[i+1]);
  const float S2 = r[24];
  const float S1 = mm<MX>(r[16], S2);
  const float S0 = mm<MX>(r[8],  S1);
#pragma unroll
  for (int i = 0;  i < 8;  ++i) r[i] = mm<MX>(r[i], S0);
#pragma unroll
  for (int i = 8;  i < 16; ++i) r[i] = mm<MX>(r[i], S1);
#pragma unroll
  for (int i = 16; i < 24; ++i) r[i] = mm<MX>(r[i], S2);

  // Top prefix within blocks of 8 + head cascade
#pragma unroll
  for (int b = 0; b < 4; ++b)
#pragma unroll
    for (int i = 8*b + 1; i < 8*b + 8; ++i) T[i] = mm<MX>(T[i-1], T[i]);
  const float G0 = mm<MX>(Base, T[7]);
  const float G1 = mm<MX>(G0,   T[15]);
  const float G2 = mm<MX>(G1,   T[23]);

  // out[i] = mm(S[i], head, T[i])
#pragma unroll
  for (int i = 0;  i < 8;  ++i) r[i] = mm<MX>(r[i], mm<MX>(Base, T[i]));
#pragma unroll
  for (int i = 8;  i < 16; ++i) r[i] = mm<MX>(r[i], mm<MX>(G0, T[i]));
#pragma unroll
  for (int i = 16; i < 24; ++i) r[i] = mm<MX>(r[i], mm<MX>(G1, T[i]));
#pragma unroll
  for (int i = 24; i < 32; ++i) r[i] = mm<MX>(r[i], mm<MX>(G2, T[i]));

  edge_zero(r, goff, tid, edge);
  writeback(r, buf, b4);
}

// K = 25: chunk A (i in [0,16)) straddles 16; chunk B (i in [16,32)) straddles
// 32. WB=false leaves outputs in r with no barriers (final stage).
template<bool MX, bool WB>
__device__ __forceinline__ void stage_25(float* r, float4* buf, int tid,
                                         int goff, bool edge) {
  const int b4 = tid * EF4;
  const int bh = min(b4, 2034);             // max slot bh+13 <= 2047
  float h[24];                              // halo floats [32..55]
#pragma unroll
  for (int j = 0; j < 6; ++j) {
    float4 v = buf[swz(bh + 8 + j)];
    h[4*j] = v.x; h[4*j+1] = v.y; h[4*j+2] = v.z; h[4*j+3] = v.w;
  }
  if constexpr (WB) __syncthreads();

  // t = prefix over raw r[24..31] (before in-place S destroys it)
  float t[8];
  t[0] = r[24];
#pragma unroll
  for (int i = 1; i < 8; ++i) t[i] = mm<MX>(t[i-1], r[24+i]);
  // S_B over r[16..31] (blocked)
#pragma unroll
  for (int i = 30; i >= 24; --i) r[i] = mm<MX>(r[i], r[i+1]);
#pragma unroll
  for (int i = 22; i >= 16; --i) r[i] = mm<MX>(r[i], r[i+1]);
  const float cA = r[16];                   // mm(raw r[16..23])
  const float A3 = r[24];
#pragma unroll
  for (int i = 16; i < 24; ++i) r[i] = mm<MX>(r[i], A3);
  // S_A over r[0..15]
#pragma unroll
  for (int i = 14; i >= 8; --i) r[i] = mm<MX>(r[i], r[i+1]);
#pragma unroll
  for (int i = 6;  i >= 0; --i) r[i] = mm<MX>(r[i], r[i+1]);
  const float A1 = r[8];
#pragma unroll
  for (int i = 0; i < 8; ++i) r[i] = mm<MX>(r[i], A1);
  // halo prefix in blocks of 8
#pragma unroll
  for (int b = 0; b < 3; ++b)
#pragma unroll
    for (int i = 8*b + 1; i < 8*b + 8; ++i) h[i] = mm<MX>(h[i-1], h[i]);
  const float aB  = h[7];                   // mm(abs 32..39)
  const float cA2 = mm<MX>(cA, t[7]);       // mm(abs 16..31)
  const float G1  = mm<MX>(aB, h[15]);      // mm(abs 32..47)
  // out[i] = mm(S, head, scan)   windows [i, i+24]
#pragma unroll
  for (int i = 0;  i < 8;  ++i) r[i] = mm<MX>(r[i], mm<MX>(cA,  t[i]));
#pragma unroll
  for (int i = 8;  i < 16; ++i) r[i] = mm<MX>(r[i], mm<MX>(cA2, h[i-8]));
#pragma unroll
  for (int i = 16; i < 24; ++i) r[i] = mm<MX>(r[i], mm<MX>(aB,  h[i-8]));
#pragma unroll
  for (int i = 24; i < 32; ++i) r[i] = mm<MX>(r[i], mm<MX>(G1,  h[i-8]));

  if constexpr (WB) {
    edge_zero(r, goff, tid, edge);
    writeback(r, buf, b4);
  }
}

__global__ __launch_bounds__(BLOCK)
void morph_co_kernel(const float* __restrict__ x, float* __restrict__ out) {
  __shared__ float4 buf[BUF_SLOTS];

  const int tid  = threadIdx.x;
  const int tile = blockIdx.x;
  const int row  = blockIdx.y;
  const float* __restrict__ xrow = x   + (size_t)row * L_ROW;
  float* __restrict__       orow = out + (size_t)row * L_ROW;

  // c0 = global input index of buffer float 0; 4-aligned; halo 76 left.
  // Final outputs land at buffer floats [2, T_VALID+2) -> row pos ob + l - 2.
  const int c0 = tile * T_VALID - 76;
  const bool edge = (tile == 0) || (tile == N_TILES - 1);

  float r[E];

  if (!edge) {
    // ---- staging: async global -> LDS, swizzled via pre-swizzled source
    const int w = tid >> 6, lane = tid & 63;
#pragma unroll
    for (int k = 0; k < 8; ++k) {
      const int q0 = k * 256 + w * 64;
      const float* g = xrow + c0 + 4 * swz(q0 + lane);
      __builtin_amdgcn_global_load_lds(
          (const __attribute__((address_space(1))) void*)g,
          (__attribute__((address_space(3))) void*)(&buf[q0]), 16, 0, 0);
    }
    // own block straight from global (same L2 lines, off the LDS pipe)
    const float* gb = xrow + c0 + tid * E;
#pragma unroll
    for (int j = 0; j < EF4; ++j) {
      float4 v = *reinterpret_cast<const float4*>(gb + 4 * j);
      r[4*j] = v.x; r[4*j+1] = v.y; r[4*j+2] = v.z; r[4*j+3] = v.w;
    }
    __syncthreads();

    // interior: max51 -> min75 (= min25∘min51) -> max25; pads never reached
    stage_big<51, true >(r, buf, tid, 0, false);
    stage_big<75, false>(r, buf, tid, 0, false);
    stage_25 <true, false>(r, buf, tid, 0, false);
  } else {
    // ---- staging with zero-fill outside the row (input zero pad)
#pragma unroll
    for (int k = 0; k < 8; ++k) {
      const int s = k * BLOCK + tid;
      const int g = c0 + 4 * s;
      float4 v;
      if (g >= 0 && g + 3 < L_ROW) {
        v = *reinterpret_cast<const float4*>(xrow + g);
      } else {
        v.x = ((unsigned)(g + 0) < (unsigned)L_ROW) ? xrow[g + 0] : 0.0f;
        v.y = ((unsigned)(g + 1) < (unsigned)L_ROW) ? xrow[g + 1] : 0.0f;
        v.z = ((unsigned)(g + 2) < (unsigned)L_ROW) ? xrow[g + 2] : 0.0f;
        v.w = ((unsigned)(g + 3) < (unsigned)L_ROW) ? xrow[g + 3] : 0.0f;
      }
      buf[swz(s)] = v;
    }
    __syncthreads();
    {
      const int b4 = tid * EF4;
#pragma unroll
      for (int j = 0; j < EF4; ++j) {
        float4 v = buf[swz(b4 + j)];
        r[4*j] = v.x; r[4*j+1] = v.y; r[4*j+2] = v.z; r[4*j+3] = v.w;
      }
    }
    // exact chain with per-stage zero padding (offsets 25/50/62/74);
    // final stage clamp is subsumed by the masked store below.
    stage_big<51, true >(r, buf, tid, c0 + 25, true);
    stage_big<51, false>(r, buf, tid, c0 + 50, true);
    stage_25 <false, true >(r, buf, tid, c0 + 62, true);
    stage_25 <true,  false>(r, buf, tid, 0, false);
  }

  // ---- direct store: r[i] -> row position ob + tid*E + i - 2, masked to
  // [ob, ob+n). Base is 8B-aligned -> 8B non-temporal stores.
  const int ob = tile * T_VALID;
  const int n  = min(T_VALID, L_ROW - ob);
  float* op = orow + ob;
  const int s_base = tid * E - 2;
#pragma unroll
  for (int j = 0; j < 16; ++j) {
    const int s0 = s_base + 2 * j;
    if ((unsigned)s0 < (unsigned)n) {
      f32x2 v = {r[2*j], r[2*j + 1]};
      __builtin_nontemporal_store(v, reinterpret_cast<f32x2*>(op + s0));
    }
  }
}

extern "C" void kernel_launch(void* const* d_in, const int* in_sizes, int n_in,
                              void* d_out, int out_size, void* d_ws, size_t ws_size,
                              hipStream_t stream) {
  const float* x = (const float*)d_in[0];
  float* out = (float*)d_out;
  dim3 grid(N_TILES, N_ROWS);
  morph_co_kernel<<<grid, BLOCK, 0, stream>>>(x, out);
}

// Round 8
// 67.812 us; speedup vs baseline: 10.3139x; 10.3139x over previous
//
#include <hip/hip_runtime.h>

// MorphologicalLayer: ops='co', windows=[51,25] on [16, 8, 262144] f32.
//   y1 = max51(zp(x)); y2 = min51(zp(y1)); y3 = min25(zp(y2)); y4 = max25(zp(y3))
// Interior tiles fuse min51∘min25 = min75 (3 stages); the two edge tiles run
// the exact 4-stage chain with per-stage zero clamps.
// Two-level (blocked-8 + cascade) suffix/prefix scans in registers; own
// 32-elem block lives in registers across stages (loaded straight from
// global); halo re-read from LDS; final outputs rotated 2 floats via LDS
// pair-exchange, then stored as aligned float4 cached stores (no LDS
// round-trip of the full tile, no NT — L2 merges full lines).

#define L_ROW   262144
#define N_ROWS  128          // B*C = 16*8
#define BLOCK   256
#define E       32           // elements per thread
#define EF4     8            // E/4
#define T_VALID 7996         // valid outputs per tile (4-aligned)
#define N_TILES 33           // ceil(262144 / 7996)
#define BUF_SLOTS 2048       // 32 KiB exactly -> 5 blocks/CU LDS-wise

// XOR swizzle at float4 granularity: spreads per-thread 128B-strided accesses
// across all 8 bank-quads. Involution, bijective on mult-of-8 ranges.
__device__ __forceinline__ int swz(int s) { return s ^ ((s >> 3) & 7); }

template<bool MX>
__device__ __forceinline__ float mm(float a, float b) {
  return MX ? fmaxf(a, b) : fminf(a, b);
}

__device__ __forceinline__ void edge_zero(float* r, int goff, int tid, bool edge) {
  if (edge) {
    const int base = goff + tid * E;
#pragma unroll
    for (int i = 0; i < E; ++i)
      if ((unsigned)(base + i) >= (unsigned)L_ROW) r[i] = 0.0f;
  }
}

__device__ __forceinline__ void writeback(const float* r, float4* buf, int b4) {
#pragma unroll
  for (int j = 0; j < EF4; ++j)
    buf[swz(b4 + j)] = make_float4(r[4*j], r[4*j+1], r[4*j+2], r[4*j+3]);
  __syncthreads();
}

// K in {51, 75}: all windows [i, i+K-1], i in [0,32), straddle the boundary
// at 32. out[i] = mm(S[i], Base&Top prefix at i+K-1). Always writes back.
template<int K, bool MX>
__device__ __forceinline__ void stage_big(float* r, float4* buf, int tid,
                                          int goff, bool edge) {
  constexpr int BLEN = K - 33;              // 18 / 42 (== 2 mod 4)
  constexpr int BN   = (BLEN + 2) / 4;      // 5 / 11 base-side f4 slots
  const int b4 = tid * EF4;
  const int bh = min(b4, 2032 - BN);        // max slot bh+15+BN <= 2047

  // Base = mm over halo floats [32 .. K-2], lane-wise accumulators
  float4 v0 = buf[swz(bh + 8)];
  float a0 = v0.x, a1 = v0.y, a2 = v0.z, a3 = v0.w;
#pragma unroll
  for (int j = 1; j < BN - 1; ++j) {
    float4 v = buf[swz(bh + 8 + j)];
    a0 = mm<MX>(a0, v.x); a1 = mm<MX>(a1, v.y);
    a2 = mm<MX>(a2, v.z); a3 = mm<MX>(a3, v.w);
  }
  float4 vl = buf[swz(bh + 8 + BN - 1)];    // 2 base floats + T[0], T[1]
  const float Base = mm<MX>(mm<MX>(mm<MX>(a0, a1), mm<MX>(a2, a3)),
                            mm<MX>(vl.x, vl.y));
  // Top: halo floats [K-1 .. K+30]
  float T[34];
  T[0] = vl.z; T[1] = vl.w;
#pragma unroll
  for (int j = 0; j < 8; ++j) {
    float4 v = buf[swz(bh + 8 + BN + j)];
    T[2+4*j] = v.x; T[3+4*j] = v.y; T[4+4*j] = v.z; T[5+4*j] = v.w;
  }
  __syncthreads();   // all halo reads complete before any in-place write

  // S[i] = mm(r[i..31]) via blocked-8 suffix + cascade (in place)
#pragma unroll
  for (int b = 0; b < 4; ++b)
#pragma unroll
    for (int i = 8*b + 6; i >= 8*b; --i) r[i] = mm<MX>(r[i], r[i+1]);
  const float S2 = r[24];
  const float S1 = mm<MX>(r[16], S2);
  const float S0 = mm<MX>(r[8],  S1);
#pragma unroll
  for (int i = 0;  i < 8;  ++i) r[i] = mm<MX>(r[i], S0);
#pragma unroll
  for (int i = 8;  i < 16; ++i) r[i] = mm<MX>(r[i], S1);
#pragma unroll
  for (int i = 16; i < 24; ++i) r[i] = mm<MX>(r[i], S2);

  // Top prefix within blocks of 8 + head cascade
#pragma unroll
  for (int b = 0; b < 4; ++b)
#pragma unroll
    for (int i = 8*b + 1; i < 8*b + 8; ++i) T[i] = mm<MX>(T[i-1], T[i]);
  const float G0 = mm<MX>(Base, T[7]);
  const float G1 = mm<MX>(G0,   T[15]);
  const float G2 = mm<MX>(G1,   T[23]);

  // out[i] = mm(S[i], head, T[i])
#pragma unroll
  for (int i = 0;  i < 8;  ++i) r[i] = mm<MX>(r[i], mm<MX>(Base, T[i]));
#pragma unroll
  for (int i = 8;  i < 16; ++i) r[i] = mm<MX>(r[i], mm<MX>(G0, T[i]));
#pragma unroll
  for (int i = 16; i < 24; ++i) r[i] = mm<MX>(r[i], mm<MX>(G1, T[i]));
#pragma unroll
  for (int i = 24; i < 32; ++i) r[i] = mm<MX>(r[i], mm<MX>(G2, T[i]));

  edge_zero(r, goff, tid, edge);
  writeback(r, buf, b4);
}

// K = 25: chunk A (i in [0,16)) straddles 16; chunk B (i in [16,32)) straddles
// 32. WB=false leaves outputs in r, no writeback (final stage).
template<bool MX, bool WB>
__device__ __forceinline__ void stage_25(float* r, float4* buf, int tid,
                                         int goff, bool edge) {
  const int b4 = tid * EF4;
  const int bh = min(b4, 2034);             // max slot bh+13 <= 2047
  float h[24];                              // halo floats [32..55]
#pragma unroll
  for (int j = 0; j < 6; ++j) {
    float4 v = buf[swz(bh + 8 + j)];
    h[4*j] = v.x; h[4*j+1] = v.y; h[4*j+2] = v.z; h[4*j+3] = v.w;
  }
  __syncthreads();   // halo reads complete (WB path: before overwrite;
                     // final path: before the pair-exchange reuses buf)

  // t = prefix over raw r[24..31] (before in-place S destroys it)
  float t[8];
  t[0] = r[24];
#pragma unroll
  for (int i = 1; i < 8; ++i) t[i] = mm<MX>(t[i-1], r[24+i]);
  // S_B over r[16..31] (blocked)
#pragma unroll
  for (int i = 30; i >= 24; --i) r[i] = mm<MX>(r[i], r[i+1]);
#pragma unroll
  for (int i = 22; i >= 16; --i) r[i] = mm<MX>(r[i], r[i+1]);
  const float cA = r[16];                   // mm(raw r[16..23])
  const float A3 = r[24];
#pragma unroll
  for (int i = 16; i < 24; ++i) r[i] = mm<MX>(r[i], A3);
  // S_A over r[0..15]
#pragma unroll
  for (int i = 14; i >= 8; --i) r[i] = mm<MX>(r[i], r[i+1]);
#pragma unroll
  for (int i = 6;  i >= 0; --i) r[i] = mm<MX>(r[i], r[i+1]);
  const float A1 = r[8];
#pragma unroll
  for (int i = 0; i < 8; ++i) r[i] = mm<MX>(r[i], A1);
  // halo prefix in blocks of 8
#pragma unroll
  for (int b = 0; b < 3; ++b)
#pragma unroll
    for (int i = 8*b + 1; i < 8*b + 8; ++i) h[i] = mm<MX>(h[i-1], h[i]);
  const float aB  = h[7];                   // mm(abs 32..39)
  const float cA2 = mm<MX>(cA, t[7]);       // mm(abs 16..31)
  const float G1  = mm<MX>(aB, h[15]);      // mm(abs 32..47)
  // out[i] = mm(S, head, scan)   windows [i, i+24]
#pragma unroll
  for (int i = 0;  i < 8;  ++i) r[i] = mm<MX>(r[i], mm<MX>(cA,  t[i]));
#pragma unroll
  for (int i = 8;  i < 16; ++i) r[i] = mm<MX>(r[i], mm<MX>(cA2, h[i-8]));
#pragma unroll
  for (int i = 16; i < 24; ++i) r[i] = mm<MX>(r[i], mm<MX>(aB,  h[i-8]));
#pragma unroll
  for (int i = 24; i < 32; ++i) r[i] = mm<MX>(r[i], mm<MX>(G1,  h[i-8]));

  if constexpr (WB) {
    edge_zero(r, goff, tid, edge);
    writeback(r, buf, b4);
  }
}

__global__ __launch_bounds__(BLOCK)
void morph_co_kernel(const float* __restrict__ x, float* __restrict__ out) {
  __shared__ float4 buf[BUF_SLOTS];

  const int tid  = threadIdx.x;
  const int tile = blockIdx.x;
  const int row  = blockIdx.y;
  const float* __restrict__ xrow = x   + (size_t)row * L_ROW;
  float* __restrict__       orow = out + (size_t)row * L_ROW;

  // c0 = global input index of buffer float 0; 4-aligned; halo 76 left.
  // Final outputs land at buffer floats [2, T_VALID+2) -> row pos ob + l - 2.
  const int c0 = tile * T_VALID - 76;
  const bool edge = (tile == 0) || (tile == N_TILES - 1);

  float r[E];

  if (!edge) {
    // ---- staging: async global -> LDS, swizzled via pre-swizzled source
    const int w = tid >> 6, lane = tid & 63;
#pragma unroll
    for (int k = 0; k < 8; ++k) {
      const int q0 = k * 256 + w * 64;
      const float* g = xrow + c0 + 4 * swz(q0 + lane);
      __builtin_amdgcn_global_load_lds(
          (const __attribute__((address_space(1))) void*)g,
          (__attribute__((address_space(3))) void*)(&buf[q0]), 16, 0, 0);
    }
    // own block straight from global (same L2 lines, off the LDS pipe)
    const float* gb = xrow + c0 + tid * E;
#pragma unroll
    for (int j = 0; j < EF4; ++j) {
      float4 v = *reinterpret_cast<const float4*>(gb + 4 * j);
      r[4*j] = v.x; r[4*j+1] = v.y; r[4*j+2] = v.z; r[4*j+3] = v.w;
    }
    __syncthreads();

    // interior: max51 -> min75 (= min25∘min51) -> max25; pads never reached
    stage_big<51, true >(r, buf, tid, 0, false);
    stage_big<75, false>(r, buf, tid, 0, false);
    stage_25 <true, false>(r, buf, tid, 0, false);
  } else {
    // ---- staging with zero-fill outside the row (input zero pad)
#pragma unroll
    for (int k = 0; k < 8; ++k) {
      const int s = k * BLOCK + tid;
      const int g = c0 + 4 * s;
      float4 v;
      if (g >= 0 && g + 3 < L_ROW) {
        v = *reinterpret_cast<const float4*>(xrow + g);
      } else {
        v.x = ((unsigned)(g + 0) < (unsigned)L_ROW) ? xrow[g + 0] : 0.0f;
        v.y = ((unsigned)(g + 1) < (unsigned)L_ROW) ? xrow[g + 1] : 0.0f;
        v.z = ((unsigned)(g + 2) < (unsigned)L_ROW) ? xrow[g + 2] : 0.0f;
        v.w = ((unsigned)(g + 3) < (unsigned)L_ROW) ? xrow[g + 3] : 0.0f;
      }
      buf[swz(s)] = v;
    }
    __syncthreads();
    {
      const int b4 = tid * EF4;
#pragma unroll
      for (int j = 0; j < EF4; ++j) {
        float4 v = buf[swz(b4 + j)];
        r[4*j] = v.x; r[4*j+1] = v.y; r[4*j+2] = v.z; r[4*j+3] = v.w;
      }
    }
    // exact chain with per-stage zero padding (offsets 25/50/62/74);
    // final-stage clamp is subsumed by the masked store below (stores are
    // confined to [ob, ob+n) which lies inside [0, L)).
    stage_big<51, true >(r, buf, tid, c0 + 25, true);
    stage_big<51, false>(r, buf, tid, c0 + 50, true);
    stage_25 <false, true >(r, buf, tid, c0 + 62, true);
    stage_25 <true,  false>(r, buf, tid, 0, false);
  }

  // ---- rotate by 2 floats via LDS pair-exchange, then aligned f4 stores.
  // Thread t's r[i] is row pos ob + t*32 + i - 2; after grabbing thread
  // t+1's (r[0], r[1]) we can store [ob + t*32, ob + t*32 + 32) aligned.
  float* pr = reinterpret_cast<float*>(buf);   // buf free after final stage
  pr[2 * tid]     = r[0];                      // stride-2 across lanes: 2-way
  pr[2 * tid + 1] = r[1];                      // bank alias only (free)
  __syncthreads();
  const int nb = (2 * tid + 2) & 511;          // thread (t+1)&255's pair
  const float n0 = pr[nb], n1 = pr[nb + 1];

  const int ob = tile * T_VALID;
  const int n  = min(T_VALID, L_ROW - ob);     // always mult of 4
  float4* og = reinterpret_cast<float4*>(orow + ob);
  const int base = tid * E;
#pragma unroll
  for (int j = 0; j < 8; ++j) {
    const int p = base + 4 * j;
    if (p < n) {
      float4 v = (j < 7)
          ? make_float4(r[4*j+2], r[4*j+3], r[4*j+4], r[4*j+5])
          : make_float4(r[30],    r[31],    n0,       n1);
      og[p >> 2] = v;
    }
  }
}

extern "C" void kernel_launch(void* const* d_in, const int* in_sizes, int n_in,
                              void* d_out, int out_size, void* d_ws, size_t ws_size,
                              hipStream_t stream) {
  const float* x = (const float*)d_in[0];
  float* out = (float*)d_out;
  dim3 grid(N_TILES, N_ROWS);
  morph_co_kernel<<<grid, BLOCK, 0, stream>>>(x, out);
}

// Round 10
// 48.923 us; speedup vs baseline: 14.2960x; 1.3861x over previous
//
#include <hip/hip_runtime.h>

// MorphologicalLayer: ops='co', windows=[51,25] on [16, 8, 262144] f32.
//   y1 = max51(zp(x)); y2 = min51(zp(y1)); y3 = min25(zp(y2)); y4 = max25(zp(y3))
// Wave-independent chunks: each wave owns 1944 outputs (2112 floats staged in
// a private LDS region). All halo exchange is wave-internal LDS (per-wave DS
// FIFO + data deps make it race-free) -> ZERO __syncthreads in the kernel.
// Interior chunks fuse min51∘min25 = min75 (3 stages); first/last chunk of
// each row run the exact 4-stage chain with per-stage zero clamps.
// Validity chain (interior): stage1 valid [0,2048); stage2(K75, lane63
// clamped) valid [0,1974); stage3(K25) valid [0,1950); claimed [2,1946). OK.

#define L_ROW   262144
#define N_ROWS  128          // B*C = 16*8
#define BLOCK   256          // 4 independent waves
#define E       32           // elements per lane
#define EF4     8            // E/4
#define T_W     1944         // claimed outputs per wave chunk (mult of 4)
#define N_CHUNKS 135         // ceil(262144 / 1944)
#define NSLOT   528          // f4 slots per wave region (2112 floats, 8448 B)

typedef float f32x2 __attribute__((ext_vector_type(2)));

// XOR swizzle at float4 granularity: spreads per-lane 128B-strided accesses
// across all 8 bank-quads. Involution, bijective on mult-of-8 ranges.
__device__ __forceinline__ int swz(int s) { return s ^ ((s >> 3) & 7); }

// Compiler-only memory fence: DS ops from one wave execute in program order
// in HW; this stops the compiler reordering them (per-thread index ranges are
// disjoint, so it otherwise legally could).
#define WFENCE() asm volatile("" ::: "memory")

template<bool MX>
__device__ __forceinline__ float mm(float a, float b) {
  return MX ? fmaxf(a, b) : fminf(a, b);
}

__device__ __forceinline__ void edge_zero(float* r, int goff, int lane, bool edge) {
  if (edge) {
    const int base = goff + lane * E;
#pragma unroll
    for (int i = 0; i < E; ++i)
      if ((unsigned)(base + i) >= (unsigned)L_ROW) r[i] = 0.0f;
  }
}

__device__ __forceinline__ void writeback(const float* r, float4* buf, int b4) {
  WFENCE();   // this stage's halo reads stay above the stores
#pragma unroll
  for (int j = 0; j < EF4; ++j)
    buf[swz(b4 + j)] = make_float4(r[4*j], r[4*j+1], r[4*j+2], r[4*j+3]);
  WFENCE();   // next stage's reads stay below the stores
}

// K in {51, 75}: all windows [i, i+K-1], i in [0,32), straddle the boundary
// at 32. out[i] = mm(S[i], Base&Top prefix at i+K-1). Writes back for
// neighbors. Lanes whose halo reads would exceed the region are clamped
// (K-DEPENDENT bound: max slot read is bh+15+BN); their outputs are garbage
// but lie beyond the claimed range (see validity chain in header).
template<int K, bool MX>
__device__ __forceinline__ void stage_big(float* r, float4* buf, int lane,
                                          int goff, bool edge) {
  constexpr int BLEN = K - 33;              // 18 / 42 (== 2 mod 4)
  constexpr int BN   = (BLEN + 2) / 4;      // 5 / 11 base-side f4 slots
  const int b4 = lane * EF4;
  const int bh = min(b4, NSLOT - 16 - BN);  // K=51: 507 (no lane clamped);
                                            // K=75: 501 (lane 63 clamped)

  // Base = mm over halo floats [32 .. K-2], lane-wise accumulators
  float4 v0 = buf[swz(bh + 8)];
  float a0 = v0.x, a1 = v0.y, a2 = v0.z, a3 = v0.w;
#pragma unroll
  for (int j = 1; j < BN - 1; ++j) {
    float4 v = buf[swz(bh + 8 + j)];
    a0 = mm<MX>(a0, v.x); a1 = mm<MX>(a1, v.y);
    a2 = mm<MX>(a2, v.z); a3 = mm<MX>(a3, v.w);
  }
  float4 vl = buf[swz(bh + 8 + BN - 1)];    // 2 base floats + T[0], T[1]
  const float Base = mm<MX>(mm<MX>(mm<MX>(a0, a1), mm<MX>(a2, a3)),
                            mm<MX>(vl.x, vl.y));
  // Top: halo floats [K-1 .. K+30]
  float T[34];
  T[0] = vl.z; T[1] = vl.w;
#pragma unroll
  for (int j = 0; j < 8; ++j) {
    float4 v = buf[swz(bh + 8 + BN + j)];
    T[2+4*j] = v.x; T[3+4*j] = v.y; T[4+4*j] = v.z; T[5+4*j] = v.w;
  }

  // S[i] = mm(r[i..31]) via blocked-8 suffix + cascade (in place)
#pragma unroll
  for (int b = 0; b < 4; ++b)
#pragma unroll
    for (int i = 8*b + 6; i >= 8*b; --i) r[i] = mm<MX>(r[i], r[i+1]);
  const float S2 = r[24];
  const float S1 = mm<MX>(r[16], S2);
  const float S0 = mm<MX>(r[8],  S1);
#pragma unroll
  for (int i = 0;  i < 8;  ++i) r[i] = mm<MX>(r[i], S0);
#pragma unroll
  for (int i = 8;  i < 16; ++i) r[i] = mm<MX>(r[i], S1);
#pragma unroll
  for (int i = 16; i < 24; ++i) r[i] = mm<MX>(r[i], S2);

  // Top prefix within blocks of 8 + head cascade
#pragma unroll
  for (int b = 0; b < 4; ++b)
#pragma unroll
    for (int i = 8*b + 1; i < 8*b + 8; ++i) T[i] = mm<MX>(T[i-1], T[i]);
  const float G0 = mm<MX>(Base, T[7]);
  const float G1 = mm<MX>(G0,   T[15]);
  const float G2 = mm<MX>(G1,   T[23]);

  // out[i] = mm(S[i], head, T[i])
#pragma unroll
  for (int i = 0;  i < 8;  ++i) r[i] = mm<MX>(r[i], mm<MX>(Base, T[i]));
#pragma unroll
  for (int i = 8;  i < 16; ++i) r[i] = mm<MX>(r[i], mm<MX>(G0, T[i]));
#pragma unroll
  for (int i = 16; i < 24; ++i) r[i] = mm<MX>(r[i], mm<MX>(G1, T[i]));
#pragma unroll
  for (int i = 24; i < 32; ++i) r[i] = mm<MX>(r[i], mm<MX>(G2, T[i]));

  edge_zero(r, goff, lane, edge);
  writeback(r, buf, b4);
}

// K = 25: chunk A (i in [0,16)) straddles 16; chunk B (i in [16,32)) straddles 32.
template<bool MX>
__device__ __forceinline__ void stage_25(float* r, float4* buf, int lane,
                                         int goff, bool edge) {
  const int b4 = lane * EF4;
  float h[24];                              // halo floats [32..55]
#pragma unroll
  for (int j = 0; j < 6; ++j) {
    float4 v = buf[swz(b4 + 8 + j)];        // max slot 504+13 = 517 < 528
    h[4*j] = v.x; h[4*j+1] = v.y; h[4*j+2] = v.z; h[4*j+3] = v.w;
  }

  // t = prefix over raw r[24..31] (before in-place S destroys it)
  float t[8];
  t[0] = r[24];
#pragma unroll
  for (int i = 1; i < 8; ++i) t[i] = mm<MX>(t[i-1], r[24+i]);
  // S_B over r[16..31] (blocked)
#pragma unroll
  for (int i = 30; i >= 24; --i) r[i] = mm<MX>(r[i], r[i+1]);
#pragma unroll
  for (int i = 22; i >= 16; --i) r[i] = mm<MX>(r[i], r[i+1]);
  const float cA = r[16];                   // mm(raw r[16..23])
  const float A3 = r[24];
#pragma unroll
  for (int i = 16; i < 24; ++i) r[i] = mm<MX>(r[i], A3);
  // S_A over r[0..15]
#pragma unroll
  for (int i = 14; i >= 8; --i) r[i] = mm<MX>(r[i], r[i+1]);
#pragma unroll
  for (int i = 6;  i >= 0; --i) r[i] = mm<MX>(r[i], r[i+1]);
  const float A1 = r[8];
#pragma unroll
  for (int i = 0; i < 8; ++i) r[i] = mm<MX>(r[i], A1);
  // halo prefix in blocks of 8
#pragma unroll
  for (int b = 0; b < 3; ++b)
#pragma unroll
    for (int i = 8*b + 1; i < 8*b + 8; ++i) h[i] = mm<MX>(h[i-1], h[i]);
  const float aB  = h[7];                   // mm(halo 32..39)
  const float cA2 = mm<MX>(cA, t[7]);       // mm(own 16..31)
  const float G1  = mm<MX>(aB, h[15]);      // mm(halo 32..47)
  // out[i] = mm(S, head, scan)   windows [i, i+24]
#pragma unroll
  for (int i = 0;  i < 8;  ++i) r[i] = mm<MX>(r[i], mm<MX>(cA,  t[i]));
#pragma unroll
  for (int i = 8;  i < 16; ++i) r[i] = mm<MX>(r[i], mm<MX>(cA2, h[i-8]));
#pragma unroll
  for (int i = 16; i < 24; ++i) r[i] = mm<MX>(r[i], mm<MX>(aB,  h[i-8]));
#pragma unroll
  for (int i = 24; i < 32; ++i) r[i] = mm<MX>(r[i], mm<MX>(G1,  h[i-8]));

  edge_zero(r, goff, lane, edge);
  writeback(r, buf, b4);
}

__global__ __launch_bounds__(BLOCK)
void morph_co_kernel(const float* __restrict__ x, float* __restrict__ out) {
  __shared__ float4 lds4[4 * NSLOT];        // 33792 B -> 4 blocks/CU

  const int w    = threadIdx.x >> 6;
  const int lane = threadIdx.x & 63;
  const int c    = blockIdx.x * 4 + w;      // chunk index within the row
  const int row  = blockIdx.y;
  if (c >= N_CHUNKS) return;                // no barriers in kernel: legal

  float4* buf = lds4 + w * NSLOT;           // private per-wave region
  const float* __restrict__ xrow = x   + (size_t)row * L_ROW;
  float* __restrict__       orow = out + (size_t)row * L_ROW;

  const int ob = c * T_W;                   // claimed outputs [ob, ob+T_W)
  const int c0 = ob - 76;                   // buffer float 0 = x[c0]; 4-aligned
  const bool edge = (c == 0) || (c == N_CHUNKS - 1);
  const int b4 = lane * EF4;
  float r[E];

  // ---- staging: global -> private LDS region (swizzled layout)
  if (!edge) {
#pragma unroll
    for (int it = 0; it < 9; ++it) {
      const int s = it * 64 + lane;
      if (s < NSLOT) {
        const float* g = xrow + c0 + 4 * swz(s);   // pre-swizzled source
        __builtin_amdgcn_global_load_lds(
            (const __attribute__((address_space(1))) void*)g,
            (__attribute__((address_space(3))) void*)(&buf[it * 64]), 16, 0, 0);
      }
    }
    asm volatile("s_waitcnt vmcnt(0)" ::: "memory");
  } else {
#pragma unroll
    for (int it = 0; it < 9; ++it) {
      const int s = it * 64 + lane;
      if (s < NSLOT) {
        const int g = c0 + 4 * s;
        float4 v;
        v.x = ((unsigned)(g + 0) < (unsigned)L_ROW) ? xrow[g + 0] : 0.0f;
        v.y = ((unsigned)(g + 1) < (unsigned)L_ROW) ? xrow[g + 1] : 0.0f;
        v.z = ((unsigned)(g + 2) < (unsigned)L_ROW) ? xrow[g + 2] : 0.0f;
        v.w = ((unsigned)(g + 3) < (unsigned)L_ROW) ? xrow[g + 3] : 0.0f;
        buf[swz(s)] = v;
      }
    }
    WFENCE();
  }

  // own block -> registers (persists across stages)
#pragma unroll
  for (int j = 0; j < EF4; ++j) {
    float4 v = buf[swz(b4 + j)];
    r[4*j] = v.x; r[4*j+1] = v.y; r[4*j+2] = v.z; r[4*j+3] = v.w;
  }

  if (!edge) {
    // interior: max51 -> min75 (= min25∘min51) -> max25; pads never reached
    stage_big<51, true >(r, buf, lane, 0, false);
    stage_big<75, false>(r, buf, lane, 0, false);
    stage_25 <true >(r, buf, lane, 0, false);
  } else {
    // exact chain with per-stage zero padding (offsets 25/50/62/74)
    stage_big<51, true >(r, buf, lane, c0 + 25, true);
    stage_big<51, false>(r, buf, lane, c0 + 50, true);
    stage_25 <false>(r, buf, lane, c0 + 62, true);
    stage_25 <true >(r, buf, lane, c0 + 74, true);
  }

  // ---- copy-out: buffer float l holds out[ob + l - 2]. Lane-contiguous LDS
  // reads; 8B-aligned f32x2 global stores (coalesced; tiles overlap 2 floats
  // with identical values - benign).
  if (!edge) {
#pragma unroll
    for (int it = 0; it < 8; ++it) {
      const int u = it * 64 + lane;
      if (u < (T_W + 2) / 4 + 1) {          // 487
        float4 v = buf[swz(u)];
        float* p = orow + ob - 2 + 4 * u;
        *reinterpret_cast<f32x2*>(p)     = f32x2{v.x, v.y};
        *reinterpret_cast<f32x2*>(p + 2) = f32x2{v.z, v.w};
      }
    }
  } else {
    const int hi = min(ob + T_W, L_ROW);
#pragma unroll
    for (int it = 0; it < 8; ++it) {
      const int u = it * 64 + lane;
      if (u < (T_W + 2) / 4 + 1) {
        float4 v = buf[swz(u)];
        const int p = ob - 2 + 4 * u;
        if (p     >= ob && p     < hi) orow[p]     = v.x;
        if (p + 1 >= ob && p + 1 < hi) orow[p + 1] = v.y;
        if (p + 2 >= ob && p + 2 < hi) orow[p + 2] = v.z;
        if (p + 3 >= ob && p + 3 < hi) orow[p + 3] = v.w;
      }
    }
  }
}

extern "C" void kernel_launch(void* const* d_in, const int* in_sizes, int n_in,
                              void* d_out, int out_size, void* d_ws, size_t ws_size,
                              hipStream_t stream) {
  const float* x = (const float*)d_in[0];
  float* out = (float*)d_out;
  dim3 grid((N_CHUNKS + 3) / 4, N_ROWS);    // 34 x 128 blocks, 4 waves each
  morph_co_kernel<<<grid, BLOCK, 0, stream>>>(x, out);
}